// Round 1
// baseline (427.128 us; speedup 1.0000x reference)
//
#include <hip/hip_runtime.h>

typedef __attribute__((ext_vector_type(8))) short bf16x8;
typedef __attribute__((ext_vector_type(4))) float f32x4;
typedef __attribute__((ext_vector_type(8))) unsigned short ushort8;
typedef __attribute__((ext_vector_type(4))) unsigned short ushort4v;

__device__ __forceinline__ unsigned short f2bf(float f) {
  unsigned int u = __float_as_uint(f);
  u = u + 0x7FFFu + ((u >> 16) & 1u);
  return (unsigned short)(u >> 16);
}

// ---------------- degree histogram ----------------
__global__ void k_deg(const int* __restrict__ dst, int* __restrict__ deg, int E) {
  int i = blockIdx.x * blockDim.x + threadIdx.x;
  if (i < E) atomicAdd(&deg[dst[i]], 1);
}

// ---------------- dinv = rsqrt(deg + self-loop) ----------------
__global__ void k_dinv(const int* __restrict__ deg, float* __restrict__ dinv, int N) {
  int i = blockIdx.x * blockDim.x + threadIdx.x;
  if (i < N) dinv[i] = rsqrtf((float)(deg[i] + 1));
}

// ---------------- 3-kernel exclusive scan over deg (1024 elems/block) ----------------
__global__ void k_scanA(const int* __restrict__ deg, int* __restrict__ bsums, int N) {
  __shared__ int s[256];
  int t = threadIdx.x;
  int base = blockIdx.x * 1024 + t * 4;
  int ts = 0;
#pragma unroll
  for (int j = 0; j < 4; ++j) { int idx = base + j; ts += (idx < N) ? deg[idx] : 0; }
  s[t] = ts; __syncthreads();
  for (int off = 1; off < 256; off <<= 1) {
    int v = (t >= off) ? s[t - off] : 0;
    __syncthreads();
    s[t] += v;
    __syncthreads();
  }
  if (t == 255) bsums[blockIdx.x] = s[255];
}

__global__ void k_scanB(int* bsums, int nb) {
  __shared__ int s[128];
  int t = threadIdx.x;
  int v = (t < nb) ? bsums[t] : 0;
  s[t] = v; __syncthreads();
  for (int off = 1; off < 128; off <<= 1) {
    int a = (t >= off) ? s[t - off] : 0;
    __syncthreads();
    s[t] += a;
    __syncthreads();
  }
  if (t < nb) bsums[t] = s[t] - v;  // exclusive
}

__global__ void k_scanC(const int* __restrict__ deg, const int* __restrict__ bsums,
                        int* __restrict__ start, int N) {
  __shared__ int s[256];
  int t = threadIdx.x;
  int base = blockIdx.x * 1024 + t * 4;
  int v[4]; int ts = 0;
#pragma unroll
  for (int j = 0; j < 4; ++j) { int idx = base + j; v[j] = (idx < N) ? deg[idx] : 0; ts += v[j]; }
  s[t] = ts; __syncthreads();
  for (int off = 1; off < 256; off <<= 1) {
    int a = (t >= off) ? s[t - off] : 0;
    __syncthreads();
    s[t] += a;
    __syncthreads();
  }
  int run = bsums[blockIdx.x] + s[t] - ts;
#pragma unroll
  for (int j = 0; j < 4; ++j) { int idx = base + j; if (idx < N) start[idx] = run; run += v[j]; }
}

// ---------------- CSR slot fill ----------------
__global__ void k_fill(const int* __restrict__ src, const int* __restrict__ dst,
                       const int* __restrict__ start, int* __restrict__ cursor,
                       int* __restrict__ ssrc, int E) {
  int i = blockIdx.x * blockDim.x + threadIdx.x;
  if (i < E) {
    int d = dst[i];
    int pos = atomicAdd(&cursor[d], 1);
    ssrc[start[d] + pos] = src[i];
  }
}

// ---------------- fused dual GEMM: hs = (x@W)*dinv ; res = x@Wr + br ----------------
// block = 256 threads (4 waves), computes 64 rows x 256 cols (128 hs | 128 res).
// LDS: xt[64][72] bf16 (padded, 2-way-free reads), wt 256x64 bf16 XOR-swizzled granules.
__global__ __launch_bounds__(256) void k_gemm(
    const float* __restrict__ x, const float* __restrict__ W, const float* __restrict__ Wr,
    const float* __restrict__ br, const float* __restrict__ dinv,
    float* __restrict__ hs, float* res, int N)
{
  __shared__ unsigned short xt[64][72];
  __shared__ unsigned short wt[256 * 64];
  int tid = threadIdx.x;
  int lane = tid & 63, wid = tid >> 6;
  int lo = lane & 15, hi = lane >> 4;
  int brow = blockIdx.x * 64;

  f32x4 acc[16];
#pragma unroll
  for (int c = 0; c < 16; ++c) acc[c] = (f32x4){0.f, 0.f, 0.f, 0.f};

  int col = tid;  // staging column 0..255 (0..127 -> W, 128..255 -> Wr)
  const float* Wsrc = (col < 128) ? (W + col) : (Wr + (col - 128));
  int cx7 = col & 7;

  for (int kt = 0; kt < 4; ++kt) {
    int k0 = kt * 64;
    // stage x tile (coalesced float4 loads, bf16 convert)
#pragma unroll
    for (int r = 0; r < 4; ++r) {
      int idx = tid + 256 * r;
      int row = idx >> 4, kq = idx & 15;
      int node = brow + row;
      float4 v = make_float4(0.f, 0.f, 0.f, 0.f);
      if (node < N) v = *(const float4*)(x + (size_t)node * 256 + k0 + kq * 4);
      ushort4v u;
      u[0] = f2bf(v.x); u[1] = f2bf(v.y); u[2] = f2bf(v.z); u[3] = f2bf(v.w);
      *(ushort4v*)(&xt[row][kq * 4]) = u;
    }
    // stage W tile transposed + XOR-swizzled (granule = 8 bf16 = 16B)
#pragma unroll
    for (int g = 0; g < 8; ++g) {
      float f[8];
#pragma unroll
      for (int j = 0; j < 8; ++j) f[j] = Wsrc[(size_t)(k0 + g * 8 + j) * 128];
      ushort8 u;
#pragma unroll
      for (int j = 0; j < 8; ++j) u[j] = f2bf(f[j]);
      *(ushort8*)(&wt[col * 64 + ((g ^ cx7) * 8)]) = u;
    }
    __syncthreads();
#pragma unroll
    for (int kk = 0; kk < 2; ++kk) {
      bf16x8 a = *(const bf16x8*)(&xt[wid * 16 + lo][kk * 32 + hi * 8]);
      int gsw = ((kk * 4 + hi) ^ (lo & 7)) * 8;
#pragma unroll
      for (int c = 0; c < 16; ++c) {
        bf16x8 b = *(const bf16x8*)(&wt[(c * 16 + lo) * 64 + gsw]);
        acc[c] = __builtin_amdgcn_mfma_f32_16x16x32_bf16(a, b, acc[c], 0, 0, 0);
      }
    }
    __syncthreads();
  }
  // epilogue: D row = hi*4+reg, col = lo (m89-verified C/D layout)
#pragma unroll
  for (int c = 0; c < 16; ++c) {
    int colo = c * 16 + lo;
#pragma unroll
    for (int rg = 0; rg < 4; ++rg) {
      int row = brow + wid * 16 + hi * 4 + rg;
      if (row < N) {
        float v = acc[c][rg];
        if (colo < 128) hs[(size_t)row * 128 + colo] = v * dinv[row];
        else            res[(size_t)row * 128 + (colo - 128)] = v + br[colo - 128];
      }
    }
  }
}

// ---------------- per-node aggregation + bias + residual + LayerNorm + ReLU ----------------
// one wave per node; lane holds channels {2*lane, 2*lane+1}. res aliases out (row-local).
__global__ __launch_bounds__(256) void k_agg(
    const float* __restrict__ hs, const float* resin,
    const float* __restrict__ dinv, const int* __restrict__ start,
    const int* __restrict__ deg, const int* __restrict__ ssrc,
    const float* __restrict__ bias, const float* __restrict__ gamma,
    const float* __restrict__ beta, float* out, int N)
{
  int node = blockIdx.x * 4 + (threadIdx.x >> 6);
  int lane = threadIdx.x & 63;
  if (node >= N) return;
  const float2* hs2 = (const float2*)hs;
  float2 a = hs2[(size_t)node * 64 + lane];  // self-loop (hs already * dinv[src])
  float ax = a.x, ay = a.y;
  int s0 = start[node], cnt = deg[node];
  for (int e = 0; e < cnt; ++e) {
    int s = ssrc[s0 + e];
    float2 v = hs2[(size_t)s * 64 + lane];
    ax += v.x; ay += v.y;
  }
  float di = dinv[node];
  float2 r  = ((const float2*)resin)[(size_t)node * 64 + lane];
  float2 bb = ((const float2*)bias)[lane];
  float vx = ax * di + bb.x + r.x;
  float vy = ay * di + bb.y + r.y;
  float sum = vx + vy;
#pragma unroll
  for (int off = 32; off >= 1; off >>= 1) sum += __shfl_xor(sum, off, 64);
  float mean = sum * (1.0f / 128.0f);
  float dx = vx - mean, dy = vy - mean;
  float sq = dx * dx + dy * dy;
#pragma unroll
  for (int off = 32; off >= 1; off >>= 1) sq += __shfl_xor(sq, off, 64);
  float rstd = rsqrtf(sq * (1.0f / 128.0f) + 1e-5f);
  float2 g  = ((const float2*)gamma)[lane];
  float2 be = ((const float2*)beta)[lane];
  float ox = fmaxf(dx * rstd * g.x + be.x, 0.0f);
  float oy = fmaxf(dy * rstd * g.y + be.y, 0.0f);
  ((float2*)out)[(size_t)node * 64 + lane] = make_float2(ox, oy);
}

extern "C" void kernel_launch(void* const* d_in, const int* in_sizes, int n_in,
                              void* d_out, int out_size, void* d_ws, size_t ws_size,
                              hipStream_t stream) {
  const float* x     = (const float*)d_in[0];
  const int*   eidx  = (const int*)d_in[1];
  const float* W     = (const float*)d_in[2];
  const float* b     = (const float*)d_in[3];
  const float* Wr    = (const float*)d_in[4];
  const float* br    = (const float*)d_in[5];
  const float* gamma = (const float*)d_in[6];
  const float* beta  = (const float*)d_in[7];
  float* out = (float*)d_out;

  int N = in_sizes[0] / 256;
  int E = in_sizes[1] / 2;
  const int* srcI = eidx;
  const int* dstI = eidx + E;

  char* w = (char*)d_ws;
  size_t off = 0;
  auto alloc = [&](size_t bytes) -> void* {
    void* p = w + off;
    off += (bytes + 255) & ~(size_t)255;
    return p;
  };
  float* hs     = (float*)alloc((size_t)N * 128 * 4);
  int*   deg    = (int*)alloc((size_t)N * 4);
  float* dinv   = (float*)alloc((size_t)N * 4);
  int*   start  = (int*)alloc((size_t)N * 4);
  int*   cursor = (int*)alloc((size_t)N * 4);
  int*   ssrc   = (int*)alloc((size_t)E * 4);
  int nb = (N + 1023) / 1024;
  int*   bsums  = (int*)alloc(((size_t)nb + 32) * 4);

  hipMemsetAsync(deg, 0, (size_t)N * 4, stream);
  hipMemsetAsync(cursor, 0, (size_t)N * 4, stream);
  k_deg  <<<(E + 255) / 256, 256, 0, stream>>>(dstI, deg, E);
  k_dinv <<<(N + 255) / 256, 256, 0, stream>>>(deg, dinv, N);
  k_scanA<<<nb, 256, 0, stream>>>(deg, bsums, N);
  k_scanB<<<1, 128, 0, stream>>>(bsums, nb);
  k_scanC<<<nb, 256, 0, stream>>>(deg, bsums, start, N);
  k_fill <<<(E + 255) / 256, 256, 0, stream>>>(srcI, dstI, start, cursor, ssrc, E);
  k_gemm <<<(N + 63) / 64, 256, 0, stream>>>(x, W, Wr, br, dinv, hs, out, N);
  k_agg  <<<(N + 3) / 4, 256, 0, stream>>>(hs, out, dinv, start, deg, ssrc, b, gamma, beta, out, N);
}

// Round 4
// 323.359 us; speedup vs baseline: 1.3209x; 1.3209x over previous
//
#include <hip/hip_runtime.h>

typedef __attribute__((ext_vector_type(8))) short bf16x8;
typedef __attribute__((ext_vector_type(4))) float f32x4;
typedef __attribute__((ext_vector_type(8))) unsigned short ushort8;
typedef __attribute__((ext_vector_type(4))) unsigned short ushort4v;

__device__ __forceinline__ unsigned short f2bf(float f) {
  unsigned int u = __float_as_uint(f);
  u = u + 0x7FFFu + ((u >> 16) & 1u);
  return (unsigned short)(u >> 16);
}
__device__ __forceinline__ float bflo(unsigned int u) { return __uint_as_float(u << 16); }
__device__ __forceinline__ float bfhi(unsigned int u) { return __uint_as_float(u & 0xFFFF0000u); }

#define GLOAD_LDS16(g, l)                                                            \
  __builtin_amdgcn_global_load_lds((const __attribute__((address_space(1))) void*)(g), \
                                   (__attribute__((address_space(3))) void*)(l), 16, 0, 0)

// ---------------- degree histogram ----------------
__global__ void k_deg(const int* __restrict__ dst, int* __restrict__ deg, int E) {
  int i = blockIdx.x * blockDim.x + threadIdx.x;
  if (i < E) atomicAdd(&deg[dst[i]], 1);
}

// ---------------- dinv = rsqrt(deg + self-loop) ----------------
__global__ void k_dinv(const int* __restrict__ deg, float* __restrict__ dinv, int N) {
  int i = blockIdx.x * blockDim.x + threadIdx.x;
  if (i < N) dinv[i] = rsqrtf((float)(deg[i] + 1));
}

// ---------------- 3-kernel exclusive scan over deg (1024 elems/block) ----------------
__global__ void k_scanA(const int* __restrict__ deg, int* __restrict__ bsums, int N) {
  __shared__ int s[256];
  int t = threadIdx.x;
  int base = blockIdx.x * 1024 + t * 4;
  int ts = 0;
#pragma unroll
  for (int j = 0; j < 4; ++j) { int idx = base + j; ts += (idx < N) ? deg[idx] : 0; }
  s[t] = ts; __syncthreads();
  for (int off = 1; off < 256; off <<= 1) {
    int v = (t >= off) ? s[t - off] : 0;
    __syncthreads();
    s[t] += v;
    __syncthreads();
  }
  if (t == 255) bsums[blockIdx.x] = s[255];
}

__global__ void k_scanB(int* bsums, int nb) {
  __shared__ int s[128];
  int t = threadIdx.x;
  int v = (t < nb) ? bsums[t] : 0;
  s[t] = v; __syncthreads();
  for (int off = 1; off < 128; off <<= 1) {
    int a = (t >= off) ? s[t - off] : 0;
    __syncthreads();
    s[t] += a;
    __syncthreads();
  }
  if (t < nb) bsums[t] = s[t] - v;  // exclusive
}

__global__ void k_scanC(const int* __restrict__ deg, const int* __restrict__ bsums,
                        int* __restrict__ start, int N) {
  __shared__ int s[256];
  int t = threadIdx.x;
  int base = blockIdx.x * 1024 + t * 4;
  int v[4]; int ts = 0;
#pragma unroll
  for (int j = 0; j < 4; ++j) { int idx = base + j; v[j] = (idx < N) ? deg[idx] : 0; ts += v[j]; }
  s[t] = ts; __syncthreads();
  for (int off = 1; off < 256; off <<= 1) {
    int a = (t >= off) ? s[t - off] : 0;
    __syncthreads();
    s[t] += a;
    __syncthreads();
  }
  int run = bsums[blockIdx.x] + s[t] - ts;
#pragma unroll
  for (int j = 0; j < 4; ++j) { int idx = base + j; if (idx < N) start[idx] = run; run += v[j]; }
}

// ---------------- CSR slot fill ----------------
__global__ void k_fill(const int* __restrict__ src, const int* __restrict__ dst,
                       const int* __restrict__ start, int* __restrict__ cursor,
                       int* __restrict__ ssrc, int E) {
  int i = blockIdx.x * blockDim.x + threadIdx.x;
  if (i < E) {
    int d = dst[i];
    int pos = atomicAdd(&cursor[d], 1);
    ssrc[start[d] + pos] = src[i];
  }
}

// ---------------- weight image prep: bf16, transposed, XOR-swizzled granules ----------------
// Wb[kt*16384 + col*64 + ((g ^ (col&7))*8) + j] = bf16( (col<128 ? W : Wr)[(kt*64+g*8+j)*128 + col%128] )
__global__ void k_prepw(const float* __restrict__ W, const float* __restrict__ Wr,
                        unsigned short* __restrict__ Wb) {
  int t = blockIdx.x * 256 + threadIdx.x;  // 0..2047
  if (t >= 2048) return;
  int col = t >> 3, g = t & 7;
  const float* Ws = (col < 128) ? (W + col) : (Wr + (col - 128));
#pragma unroll
  for (int kt = 0; kt < 4; ++kt) {
    ushort8 u;
#pragma unroll
    for (int j = 0; j < 8; ++j) u[j] = f2bf(Ws[(size_t)(kt * 64 + g * 8 + j) * 128]);
    *(ushort8*)&Wb[kt * 16384 + col * 64 + ((g ^ (col & 7)) * 8)] = u;
  }
}

// ---------------- fused dual GEMM: hs = bf16((x@W)*dinv) ; res = x@Wr + br ----------------
__global__ __launch_bounds__(256) void k_gemm(
    const float* __restrict__ x, const unsigned short* __restrict__ Wb,
    const float* __restrict__ br, const float* __restrict__ dinv,
    unsigned short* __restrict__ hs, float* res, int N)
{
  __shared__ unsigned short xt[64][72];
  __shared__ unsigned short wt[256 * 64];
  int tid = threadIdx.x;
  int lane = tid & 63, wid = tid >> 6;
  int lo = lane & 15, hi = lane >> 4;
  int brow = blockIdx.x * 64;

  f32x4 acc[16];
#pragma unroll
  for (int c = 0; c < 16; ++c) acc[c] = (f32x4){0.f, 0.f, 0.f, 0.f};

  for (int kt = 0; kt < 4; ++kt) {
    int k0 = kt * 64;
    // stage W image via async global->LDS, 16B per lane per issue (no converts)
    const unsigned short* gw = Wb + kt * 16384;
#pragma unroll
    for (int i = 0; i < 8; ++i) {
      int off = i * 2048 + tid * 8;  // ushort offset; linear in lane (16B stride)
      GLOAD_LDS16(gw + off, &wt[off]);
    }
    // stage x tile (coalesced float4 loads, bf16 convert)
#pragma unroll
    for (int r = 0; r < 4; ++r) {
      int idx = tid + 256 * r;
      int row = idx >> 4, kq = idx & 15;
      int node = brow + row;
      float4 v = make_float4(0.f, 0.f, 0.f, 0.f);
      if (node < N) v = *(const float4*)(x + (size_t)node * 256 + k0 + kq * 4);
      ushort4v u;
      u[0] = f2bf(v.x); u[1] = f2bf(v.y); u[2] = f2bf(v.z); u[3] = f2bf(v.w);
      *(ushort4v*)(&xt[row][kq * 4]) = u;
    }
    __syncthreads();
#pragma unroll
    for (int kk = 0; kk < 2; ++kk) {
      bf16x8 a = *(const bf16x8*)(&xt[wid * 16 + lo][kk * 32 + hi * 8]);
      int gsw = ((kk * 4 + hi) ^ (lo & 7)) * 8;
#pragma unroll
      for (int c = 0; c < 16; ++c) {
        bf16x8 b = *(const bf16x8*)(&wt[(c * 16 + lo) * 64 + gsw]);
        acc[c] = __builtin_amdgcn_mfma_f32_16x16x32_bf16(a, b, acc[c], 0, 0, 0);
      }
    }
    __syncthreads();
  }
  // epilogue: D row = hi*4+reg, col = lo
#pragma unroll
  for (int c = 0; c < 16; ++c) {
    int colo = c * 16 + lo;
#pragma unroll
    for (int rg = 0; rg < 4; ++rg) {
      int row = brow + wid * 16 + hi * 4 + rg;
      if (row < N) {
        float v = acc[c][rg];
        if (colo < 128) hs[(size_t)row * 128 + colo] = f2bf(v * dinv[row]);
        else            res[(size_t)row * 128 + (colo - 128)] = v + br[colo - 128];
      }
    }
  }
}

// ---------------- per-node aggregation + bias + residual + LayerNorm + ReLU ----------------
// one wave per node; lane holds channels {2*lane, 2*lane+1}; hs is bf16x2-packed uint.
// Edge loop batched 8-deep: 8 index loads, then 8 independent gathers -> MLP.
__global__ __launch_bounds__(256) void k_agg(
    const unsigned int* __restrict__ hsb, const float* resin,
    const float* __restrict__ dinv, const int* __restrict__ start,
    const int* __restrict__ deg, const int* __restrict__ ssrc,
    const float* __restrict__ bias, const float* __restrict__ gamma,
    const float* __restrict__ beta, float* out, int N)
{
  int node = blockIdx.x * 4 + (threadIdx.x >> 6);
  int lane = threadIdx.x & 63;
  if (node >= N) return;
  unsigned int su = hsb[(size_t)node * 64 + lane];  // self-loop (hs already * dinv[src])
  float ax = bflo(su), ay = bfhi(su);
  int s0 = start[node], cnt = deg[node];
  const int* sp = ssrc + s0;
  int e = 0;
  for (; e + 8 <= cnt; e += 8) {
    int i0 = sp[e + 0], i1 = sp[e + 1], i2 = sp[e + 2], i3 = sp[e + 3];
    int i4 = sp[e + 4], i5 = sp[e + 5], i6 = sp[e + 6], i7 = sp[e + 7];
    unsigned int u0 = hsb[(size_t)i0 * 64 + lane];
    unsigned int u1 = hsb[(size_t)i1 * 64 + lane];
    unsigned int u2 = hsb[(size_t)i2 * 64 + lane];
    unsigned int u3 = hsb[(size_t)i3 * 64 + lane];
    unsigned int u4 = hsb[(size_t)i4 * 64 + lane];
    unsigned int u5 = hsb[(size_t)i5 * 64 + lane];
    unsigned int u6 = hsb[(size_t)i6 * 64 + lane];
    unsigned int u7 = hsb[(size_t)i7 * 64 + lane];
    float x01 = bflo(u0) + bflo(u1), x23 = bflo(u2) + bflo(u3);
    float x45 = bflo(u4) + bflo(u5), x67 = bflo(u6) + bflo(u7);
    float y01 = bfhi(u0) + bfhi(u1), y23 = bfhi(u2) + bfhi(u3);
    float y45 = bfhi(u4) + bfhi(u5), y67 = bfhi(u6) + bfhi(u7);
    ax += (x01 + x23) + (x45 + x67);
    ay += (y01 + y23) + (y45 + y67);
  }
  for (; e + 4 <= cnt; e += 4) {
    int i0 = sp[e + 0], i1 = sp[e + 1], i2 = sp[e + 2], i3 = sp[e + 3];
    unsigned int u0 = hsb[(size_t)i0 * 64 + lane];
    unsigned int u1 = hsb[(size_t)i1 * 64 + lane];
    unsigned int u2 = hsb[(size_t)i2 * 64 + lane];
    unsigned int u3 = hsb[(size_t)i3 * 64 + lane];
    ax += (bflo(u0) + bflo(u1)) + (bflo(u2) + bflo(u3));
    ay += (bfhi(u0) + bfhi(u1)) + (bfhi(u2) + bfhi(u3));
  }
  for (; e < cnt; ++e) {
    int s = sp[e];
    unsigned int u = hsb[(size_t)s * 64 + lane];
    ax += bflo(u); ay += bfhi(u);
  }
  float di = dinv[node];
  float2 r  = ((const float2*)resin)[(size_t)node * 64 + lane];
  float2 bb = ((const float2*)bias)[lane];
  float vx = ax * di + bb.x + r.x;
  float vy = ay * di + bb.y + r.y;
  float sum = vx + vy;
#pragma unroll
  for (int off = 32; off >= 1; off >>= 1) sum += __shfl_xor(sum, off, 64);
  float mean = sum * (1.0f / 128.0f);
  float dx = vx - mean, dy = vy - mean;
  float sq = dx * dx + dy * dy;
#pragma unroll
  for (int off = 32; off >= 1; off >>= 1) sq += __shfl_xor(sq, off, 64);
  float rstd = rsqrtf(sq * (1.0f / 128.0f) + 1e-5f);
  float2 g  = ((const float2*)gamma)[lane];
  float2 be = ((const float2*)beta)[lane];
  float ox = fmaxf(dx * rstd * g.x + be.x, 0.0f);
  float oy = fmaxf(dy * rstd * g.y + be.y, 0.0f);
  ((float2*)out)[(size_t)node * 64 + lane] = make_float2(ox, oy);
}

extern "C" void kernel_launch(void* const* d_in, const int* in_sizes, int n_in,
                              void* d_out, int out_size, void* d_ws, size_t ws_size,
                              hipStream_t stream) {
  const float* x     = (const float*)d_in[0];
  const int*   eidx  = (const int*)d_in[1];
  const float* W     = (const float*)d_in[2];
  const float* b     = (const float*)d_in[3];
  const float* Wr    = (const float*)d_in[4];
  const float* br    = (const float*)d_in[5];
  const float* gamma = (const float*)d_in[6];
  const float* beta  = (const float*)d_in[7];
  float* out = (float*)d_out;

  int N = in_sizes[0] / 256;
  int E = in_sizes[1] / 2;
  const int* srcI = eidx;
  const int* dstI = eidx + E;

  char* w = (char*)d_ws;
  size_t off = 0;
  auto alloc = [&](size_t bytes) -> void* {
    void* p = w + off;
    off += (bytes + 255) & ~(size_t)255;
    return p;
  };
  unsigned short* hs   = (unsigned short*)alloc((size_t)N * 128 * 2);
  int*   deg    = (int*)alloc((size_t)N * 4);
  float* dinv   = (float*)alloc((size_t)N * 4);
  int*   start  = (int*)alloc((size_t)N * 4);
  int*   cursor = (int*)alloc((size_t)N * 4);
  int*   ssrc   = (int*)alloc((size_t)E * 4);
  unsigned short* Wb = (unsigned short*)alloc((size_t)4 * 16384 * 2);
  int nb = (N + 1023) / 1024;
  int*   bsums  = (int*)alloc(((size_t)nb + 32) * 4);

  hipMemsetAsync(deg, 0, (size_t)N * 4, stream);
  hipMemsetAsync(cursor, 0, (size_t)N * 4, stream);
  k_deg  <<<(E + 255) / 256, 256, 0, stream>>>(dstI, deg, E);
  k_dinv <<<(N + 255) / 256, 256, 0, stream>>>(deg, dinv, N);
  k_scanA<<<nb, 256, 0, stream>>>(deg, bsums, N);
  k_scanB<<<1, 128, 0, stream>>>(bsums, nb);
  k_scanC<<<nb, 256, 0, stream>>>(deg, bsums, start, N);
  k_fill <<<(E + 255) / 256, 256, 0, stream>>>(srcI, dstI, start, cursor, ssrc, E);
  k_prepw<<<8, 256, 0, stream>>>(W, Wr, Wb);
  k_gemm <<<(N + 63) / 64, 256, 0, stream>>>(x, Wb, br, dinv, hs, out, N);
  k_agg  <<<(N + 3) / 4, 256, 0, stream>>>((const unsigned int*)hs, out, dinv, start, deg, ssrc,
                                           b, gamma, beta, out, N);
}

// Round 5
// 251.682 us; speedup vs baseline: 1.6971x; 1.2848x over previous
//
#include <hip/hip_runtime.h>

typedef __attribute__((ext_vector_type(8))) short bf16x8;
typedef __attribute__((ext_vector_type(4))) float f32x4;
typedef __attribute__((ext_vector_type(8))) unsigned short ushort8;
typedef __attribute__((ext_vector_type(4))) unsigned short ushort4v;

__device__ __forceinline__ unsigned short f2bf(float f) {
  unsigned int u = __float_as_uint(f);
  u = u + 0x7FFFu + ((u >> 16) & 1u);
  return (unsigned short)(u >> 16);
}
__device__ __forceinline__ float bflo(unsigned int u) { return __uint_as_float(u << 16); }
__device__ __forceinline__ float bfhi(unsigned int u) { return __uint_as_float(u & 0xFFFF0000u); }

#define GLOAD_LDS16(g, l)                                                            \
  __builtin_amdgcn_global_load_lds((const __attribute__((address_space(1))) void*)(g), \
                                   (__attribute__((address_space(3))) void*)(l), 16, 0, 0)

// ---------------- degree histogram + per-edge rank (atomic return value) ----------------
// ONE atomic per edge total across the whole CSR build; rank write is coalesced.
__global__ void k_degrank(const int* __restrict__ dst, int* __restrict__ deg,
                          int* __restrict__ rank, int E) {
  int base = (blockIdx.x * blockDim.x + threadIdx.x) * 4;
  if (base + 3 < E) {
    int4 d = *(const int4*)(dst + base);
    int r0 = atomicAdd(&deg[d.x], 1);
    int r1 = atomicAdd(&deg[d.y], 1);
    int r2 = atomicAdd(&deg[d.z], 1);
    int r3 = atomicAdd(&deg[d.w], 1);
    *(int4*)(rank + base) = make_int4(r0, r1, r2, r3);
  } else {
    for (int e = base; e < E; ++e) rank[e] = atomicAdd(&deg[dst[e]], 1);
  }
}

// ---------------- dinv = rsqrt(deg + self-loop) ----------------
__global__ void k_dinv(const int* __restrict__ deg, float* __restrict__ dinv, int N) {
  int i = blockIdx.x * blockDim.x + threadIdx.x;
  if (i < N) dinv[i] = rsqrtf((float)(deg[i] + 1));
}

// ---------------- 3-kernel exclusive scan over deg (1024 elems/block) ----------------
__global__ void k_scanA(const int* __restrict__ deg, int* __restrict__ bsums, int N) {
  __shared__ int s[256];
  int t = threadIdx.x;
  int base = blockIdx.x * 1024 + t * 4;
  int ts = 0;
#pragma unroll
  for (int j = 0; j < 4; ++j) { int idx = base + j; ts += (idx < N) ? deg[idx] : 0; }
  s[t] = ts; __syncthreads();
  for (int off = 1; off < 256; off <<= 1) {
    int v = (t >= off) ? s[t - off] : 0;
    __syncthreads();
    s[t] += v;
    __syncthreads();
  }
  if (t == 255) bsums[blockIdx.x] = s[255];
}

__global__ void k_scanB(int* bsums, int nb) {
  __shared__ int s[128];
  int t = threadIdx.x;
  int v = (t < nb) ? bsums[t] : 0;
  s[t] = v; __syncthreads();
  for (int off = 1; off < 128; off <<= 1) {
    int a = (t >= off) ? s[t - off] : 0;
    __syncthreads();
    s[t] += a;
    __syncthreads();
  }
  if (t < nb) bsums[t] = s[t] - v;  // exclusive
}

__global__ void k_scanC(const int* __restrict__ deg, const int* __restrict__ bsums,
                        int* __restrict__ start, int N) {
  __shared__ int s[256];
  int t = threadIdx.x;
  int base = blockIdx.x * 1024 + t * 4;
  int v[4]; int ts = 0;
#pragma unroll
  for (int j = 0; j < 4; ++j) { int idx = base + j; v[j] = (idx < N) ? deg[idx] : 0; ts += v[j]; }
  s[t] = ts; __syncthreads();
  for (int off = 1; off < 256; off <<= 1) {
    int a = (t >= off) ? s[t - off] : 0;
    __syncthreads();
    s[t] += a;
    __syncthreads();
  }
  int run = bsums[blockIdx.x] + s[t] - ts;
#pragma unroll
  for (int j = 0; j < 4; ++j) { int idx = base + j; if (idx < N) start[idx] = run; run += v[j]; }
}

// ---------------- CSR slot fill (atomic-free: slot = start[dst] + rank) ----------------
__global__ void k_fill(const int* __restrict__ src, const int* __restrict__ dst,
                       const int* __restrict__ start, const int* __restrict__ rank,
                       int* __restrict__ ssrc, int E) {
  int base = (blockIdx.x * blockDim.x + threadIdx.x) * 4;
  if (base + 3 < E) {
    int4 d = *(const int4*)(dst + base);
    int4 r = *(const int4*)(rank + base);
    int4 s = *(const int4*)(src + base);
    ssrc[start[d.x] + r.x] = s.x;
    ssrc[start[d.y] + r.y] = s.y;
    ssrc[start[d.z] + r.z] = s.z;
    ssrc[start[d.w] + r.w] = s.w;
  } else {
    for (int e = base; e < E; ++e) ssrc[start[dst[e]] + rank[e]] = src[e];
  }
}

// ---------------- weight image prep: bf16, transposed, XOR-swizzled granules ----------------
__global__ void k_prepw(const float* __restrict__ W, const float* __restrict__ Wr,
                        unsigned short* __restrict__ Wb) {
  int t = blockIdx.x * 256 + threadIdx.x;  // 0..2047
  if (t >= 2048) return;
  int col = t >> 3, g = t & 7;
  const float* Ws = (col < 128) ? (W + col) : (Wr + (col - 128));
#pragma unroll
  for (int kt = 0; kt < 4; ++kt) {
    ushort8 u;
#pragma unroll
    for (int j = 0; j < 8; ++j) u[j] = f2bf(Ws[(size_t)(kt * 64 + g * 8 + j) * 128]);
    *(ushort8*)&Wb[kt * 16384 + col * 64 + ((g ^ (col & 7)) * 8)] = u;
  }
}

// ---------------- fused dual GEMM: hs = bf16((x@W)*dinv) ; res = x@Wr + br ----------------
__global__ __launch_bounds__(256) void k_gemm(
    const float* __restrict__ x, const unsigned short* __restrict__ Wb,
    const float* __restrict__ br, const float* __restrict__ dinv,
    unsigned short* __restrict__ hs, float* res, int N)
{
  __shared__ unsigned short xt[64][72];
  __shared__ unsigned short wt[256 * 64];
  int tid = threadIdx.x;
  int lane = tid & 63, wid = tid >> 6;
  int lo = lane & 15, hi = lane >> 4;
  int brow = blockIdx.x * 64;

  f32x4 acc[16];
#pragma unroll
  for (int c = 0; c < 16; ++c) acc[c] = (f32x4){0.f, 0.f, 0.f, 0.f};

  for (int kt = 0; kt < 4; ++kt) {
    int k0 = kt * 64;
    const unsigned short* gw = Wb + kt * 16384;
#pragma unroll
    for (int i = 0; i < 8; ++i) {
      int off = i * 2048 + tid * 8;  // ushort offset; linear in lane (16B stride)
      GLOAD_LDS16(gw + off, &wt[off]);
    }
#pragma unroll
    for (int r = 0; r < 4; ++r) {
      int idx = tid + 256 * r;
      int row = idx >> 4, kq = idx & 15;
      int node = brow + row;
      float4 v = make_float4(0.f, 0.f, 0.f, 0.f);
      if (node < N) v = *(const float4*)(x + (size_t)node * 256 + k0 + kq * 4);
      ushort4v u;
      u[0] = f2bf(v.x); u[1] = f2bf(v.y); u[2] = f2bf(v.z); u[3] = f2bf(v.w);
      *(ushort4v*)(&xt[row][kq * 4]) = u;
    }
    __syncthreads();
#pragma unroll
    for (int kk = 0; kk < 2; ++kk) {
      bf16x8 a = *(const bf16x8*)(&xt[wid * 16 + lo][kk * 32 + hi * 8]);
      int gsw = ((kk * 4 + hi) ^ (lo & 7)) * 8;
#pragma unroll
      for (int c = 0; c < 16; ++c) {
        bf16x8 b = *(const bf16x8*)(&wt[(c * 16 + lo) * 64 + gsw]);
        acc[c] = __builtin_amdgcn_mfma_f32_16x16x32_bf16(a, b, acc[c], 0, 0, 0);
      }
    }
    __syncthreads();
  }
#pragma unroll
  for (int c = 0; c < 16; ++c) {
    int colo = c * 16 + lo;
#pragma unroll
    for (int rg = 0; rg < 4; ++rg) {
      int row = brow + wid * 16 + hi * 4 + rg;
      if (row < N) {
        float v = acc[c][rg];
        if (colo < 128) hs[(size_t)row * 128 + colo] = f2bf(v * dinv[row]);
        else            res[(size_t)row * 128 + (colo - 128)] = v + br[colo - 128];
      }
    }
  }
}

// ---------------- per-node aggregation + bias + residual + LayerNorm + ReLU ----------------
__global__ __launch_bounds__(256) void k_agg(
    const unsigned int* __restrict__ hsb, const float* resin,
    const float* __restrict__ dinv, const int* __restrict__ start,
    const int* __restrict__ deg, const int* __restrict__ ssrc,
    const float* __restrict__ bias, const float* __restrict__ gamma,
    const float* __restrict__ beta, float* out, int N)
{
  int node = blockIdx.x * 4 + (threadIdx.x >> 6);
  int lane = threadIdx.x & 63;
  if (node >= N) return;
  unsigned int su = hsb[(size_t)node * 64 + lane];  // self-loop (hs already * dinv[src])
  float ax = bflo(su), ay = bfhi(su);
  int s0 = start[node], cnt = deg[node];
  const int* sp = ssrc + s0;
  int e = 0;
  for (; e + 8 <= cnt; e += 8) {
    int i0 = sp[e + 0], i1 = sp[e + 1], i2 = sp[e + 2], i3 = sp[e + 3];
    int i4 = sp[e + 4], i5 = sp[e + 5], i6 = sp[e + 6], i7 = sp[e + 7];
    unsigned int u0 = hsb[(size_t)i0 * 64 + lane];
    unsigned int u1 = hsb[(size_t)i1 * 64 + lane];
    unsigned int u2 = hsb[(size_t)i2 * 64 + lane];
    unsigned int u3 = hsb[(size_t)i3 * 64 + lane];
    unsigned int u4 = hsb[(size_t)i4 * 64 + lane];
    unsigned int u5 = hsb[(size_t)i5 * 64 + lane];
    unsigned int u6 = hsb[(size_t)i6 * 64 + lane];
    unsigned int u7 = hsb[(size_t)i7 * 64 + lane];
    float x01 = bflo(u0) + bflo(u1), x23 = bflo(u2) + bflo(u3);
    float x45 = bflo(u4) + bflo(u5), x67 = bflo(u6) + bflo(u7);
    float y01 = bfhi(u0) + bfhi(u1), y23 = bfhi(u2) + bfhi(u3);
    float y45 = bfhi(u4) + bfhi(u5), y67 = bfhi(u6) + bfhi(u7);
    ax += (x01 + x23) + (x45 + x67);
    ay += (y01 + y23) + (y45 + y67);
  }
  for (; e + 4 <= cnt; e += 4) {
    int i0 = sp[e + 0], i1 = sp[e + 1], i2 = sp[e + 2], i3 = sp[e + 3];
    unsigned int u0 = hsb[(size_t)i0 * 64 + lane];
    unsigned int u1 = hsb[(size_t)i1 * 64 + lane];
    unsigned int u2 = hsb[(size_t)i2 * 64 + lane];
    unsigned int u3 = hsb[(size_t)i3 * 64 + lane];
    ax += (bflo(u0) + bflo(u1)) + (bflo(u2) + bflo(u3));
    ay += (bfhi(u0) + bfhi(u1)) + (bfhi(u2) + bfhi(u3));
  }
  for (; e < cnt; ++e) {
    int s = sp[e];
    unsigned int u = hsb[(size_t)s * 64 + lane];
    ax += bflo(u); ay += bfhi(u);
  }
  float di = dinv[node];
  float2 r  = ((const float2*)resin)[(size_t)node * 64 + lane];
  float2 bb = ((const float2*)bias)[lane];
  float vx = ax * di + bb.x + r.x;
  float vy = ay * di + bb.y + r.y;
  float sum = vx + vy;
#pragma unroll
  for (int off = 32; off >= 1; off >>= 1) sum += __shfl_xor(sum, off, 64);
  float mean = sum * (1.0f / 128.0f);
  float dx = vx - mean, dy = vy - mean;
  float sq = dx * dx + dy * dy;
#pragma unroll
  for (int off = 32; off >= 1; off >>= 1) sq += __shfl_xor(sq, off, 64);
  float rstd = rsqrtf(sq * (1.0f / 128.0f) + 1e-5f);
  float2 g  = ((const float2*)gamma)[lane];
  float2 be = ((const float2*)beta)[lane];
  float ox = fmaxf(dx * rstd * g.x + be.x, 0.0f);
  float oy = fmaxf(dy * rstd * g.y + be.y, 0.0f);
  ((float2*)out)[(size_t)node * 64 + lane] = make_float2(ox, oy);
}

extern "C" void kernel_launch(void* const* d_in, const int* in_sizes, int n_in,
                              void* d_out, int out_size, void* d_ws, size_t ws_size,
                              hipStream_t stream) {
  const float* x     = (const float*)d_in[0];
  const int*   eidx  = (const int*)d_in[1];
  const float* W     = (const float*)d_in[2];
  const float* b     = (const float*)d_in[3];
  const float* Wr    = (const float*)d_in[4];
  const float* br    = (const float*)d_in[5];
  const float* gamma = (const float*)d_in[6];
  const float* beta  = (const float*)d_in[7];
  float* out = (float*)d_out;

  int N = in_sizes[0] / 256;
  int E = in_sizes[1] / 2;
  const int* srcI = eidx;
  const int* dstI = eidx + E;

  char* w = (char*)d_ws;
  size_t off = 0;
  auto alloc = [&](size_t bytes) -> void* {
    void* p = w + off;
    off += (bytes + 255) & ~(size_t)255;
    return p;
  };
  unsigned short* hs   = (unsigned short*)alloc((size_t)N * 128 * 2);
  int*   deg    = (int*)alloc((size_t)N * 4);
  float* dinv   = (float*)alloc((size_t)N * 4);
  int*   start  = (int*)alloc((size_t)N * 4);
  int*   rank   = (int*)alloc((size_t)E * 4);
  int*   ssrc   = (int*)alloc((size_t)E * 4);
  unsigned short* Wb = (unsigned short*)alloc((size_t)4 * 16384 * 2);
  int nb = (N + 1023) / 1024;
  int*   bsums  = (int*)alloc(((size_t)nb + 32) * 4);

  hipMemsetAsync(deg, 0, (size_t)N * 4, stream);
  int egrid = (E / 4 + 255) / 256 + 1;
  k_degrank<<<egrid, 256, 0, stream>>>(dstI, deg, rank, E);
  k_dinv <<<(N + 255) / 256, 256, 0, stream>>>(deg, dinv, N);
  k_scanA<<<nb, 256, 0, stream>>>(deg, bsums, N);
  k_scanB<<<1, 128, 0, stream>>>(bsums, nb);
  k_scanC<<<nb, 256, 0, stream>>>(deg, bsums, start, N);
  k_fill <<<egrid, 256, 0, stream>>>(srcI, dstI, start, rank, ssrc, E);
  k_prepw<<<8, 256, 0, stream>>>(W, Wr, Wb);
  k_gemm <<<(N + 63) / 64, 256, 0, stream>>>(x, Wb, br, dinv, hs, out, N);
  k_agg  <<<(N + 3) / 4, 256, 0, stream>>>((const unsigned int*)hs, out, dinv, start, deg, ssrc,
                                           b, gamma, beta, out, N);
}

// Round 6
// 238.662 us; speedup vs baseline: 1.7897x; 1.0546x over previous
//
#include <hip/hip_runtime.h>

typedef __attribute__((ext_vector_type(8))) short bf16x8;
typedef __attribute__((ext_vector_type(4))) float f32x4;
typedef __attribute__((ext_vector_type(8))) unsigned short ushort8;
typedef __attribute__((ext_vector_type(4))) unsigned short ushort4v;

__device__ __forceinline__ unsigned short f2bf(float f) {
  unsigned int u = __float_as_uint(f);
  u = u + 0x7FFFu + ((u >> 16) & 1u);
  return (unsigned short)(u >> 16);
}
__device__ __forceinline__ float bflo(unsigned int u) { return __uint_as_float(u << 16); }
__device__ __forceinline__ float bfhi(unsigned int u) { return __uint_as_float(u & 0xFFFF0000u); }

#define GLOAD_LDS16(g, l)                                                            \
  __builtin_amdgcn_global_load_lds((const __attribute__((address_space(1))) void*)(g), \
                                   (__attribute__((address_space(3))) void*)(l), 16, 0, 0)

// ---------------- degree histogram + per-edge rank (atomic return value) ----------------
__global__ void k_degrank(const int* __restrict__ dst, int* __restrict__ deg,
                          int* __restrict__ rank, int E) {
  int base = (blockIdx.x * blockDim.x + threadIdx.x) * 4;
  if (base + 3 < E) {
    int4 d = *(const int4*)(dst + base);
    int r0 = atomicAdd(&deg[d.x], 1);
    int r1 = atomicAdd(&deg[d.y], 1);
    int r2 = atomicAdd(&deg[d.z], 1);
    int r3 = atomicAdd(&deg[d.w], 1);
    *(int4*)(rank + base) = make_int4(r0, r1, r2, r3);
  } else {
    for (int e = base; e < E; ++e) rank[e] = atomicAdd(&deg[dst[e]], 1);
  }
}

// ---------------- dinv = rsqrt(deg + self-loop) ----------------
__global__ void k_dinv(const int* __restrict__ deg, float* __restrict__ dinv, int N) {
  int i = blockIdx.x * blockDim.x + threadIdx.x;
  if (i < N) dinv[i] = rsqrtf((float)(deg[i] + 1));
}

// ---------------- 3-kernel exclusive scan over deg (1024 elems/block) ----------------
__global__ void k_scanA(const int* __restrict__ deg, int* __restrict__ bsums, int N) {
  __shared__ int s[256];
  int t = threadIdx.x;
  int base = blockIdx.x * 1024 + t * 4;
  int ts = 0;
#pragma unroll
  for (int j = 0; j < 4; ++j) { int idx = base + j; ts += (idx < N) ? deg[idx] : 0; }
  s[t] = ts; __syncthreads();
  for (int off = 1; off < 256; off <<= 1) {
    int v = (t >= off) ? s[t - off] : 0;
    __syncthreads();
    s[t] += v;
    __syncthreads();
  }
  if (t == 255) bsums[blockIdx.x] = s[255];
}

__global__ void k_scanB(int* bsums, int nb) {
  __shared__ int s[128];
  int t = threadIdx.x;
  int v = (t < nb) ? bsums[t] : 0;
  s[t] = v; __syncthreads();
  for (int off = 1; off < 128; off <<= 1) {
    int a = (t >= off) ? s[t - off] : 0;
    __syncthreads();
    s[t] += a;
    __syncthreads();
  }
  if (t < nb) bsums[t] = s[t] - v;  // exclusive
}

__global__ void k_scanC(const int* __restrict__ deg, const int* __restrict__ bsums,
                        int* __restrict__ start, int N) {
  __shared__ int s[256];
  int t = threadIdx.x;
  int base = blockIdx.x * 1024 + t * 4;
  int v[4]; int ts = 0;
#pragma unroll
  for (int j = 0; j < 4; ++j) { int idx = base + j; v[j] = (idx < N) ? deg[idx] : 0; ts += v[j]; }
  s[t] = ts; __syncthreads();
  for (int off = 1; off < 256; off <<= 1) {
    int a = (t >= off) ? s[t - off] : 0;
    __syncthreads();
    s[t] += a;
    __syncthreads();
  }
  int run = bsums[blockIdx.x] + s[t] - ts;
#pragma unroll
  for (int j = 0; j < 4; ++j) { int idx = base + j; if (idx < N) start[idx] = run; run += v[j]; }
}

// ---------------- CSR slot fill (atomic-free: slot = start[dst] + rank) ----------------
__global__ void k_fill(const int* __restrict__ src, const int* __restrict__ dst,
                       const int* __restrict__ start, const int* __restrict__ rank,
                       int* __restrict__ ssrc, int E) {
  int base = (blockIdx.x * blockDim.x + threadIdx.x) * 4;
  if (base + 3 < E) {
    int4 d = *(const int4*)(dst + base);
    int4 r = *(const int4*)(rank + base);
    int4 s = *(const int4*)(src + base);
    ssrc[start[d.x] + r.x] = s.x;
    ssrc[start[d.y] + r.y] = s.y;
    ssrc[start[d.z] + r.z] = s.z;
    ssrc[start[d.w] + r.w] = s.w;
  } else {
    for (int e = base; e < E; ++e) ssrc[start[dst[e]] + rank[e]] = src[e];
  }
}

// ---------------- weight image prep: bf16, transposed, XOR-swizzled granules ----------------
__global__ void k_prepw(const float* __restrict__ W, const float* __restrict__ Wr,
                        unsigned short* __restrict__ Wb) {
  int t = blockIdx.x * 256 + threadIdx.x;  // 0..2047
  if (t >= 2048) return;
  int col = t >> 3, g = t & 7;
  const float* Ws = (col < 128) ? (W + col) : (Wr + (col - 128));
#pragma unroll
  for (int kt = 0; kt < 4; ++kt) {
    ushort8 u;
#pragma unroll
    for (int j = 0; j < 8; ++j) u[j] = f2bf(Ws[(size_t)(kt * 64 + g * 8 + j) * 128]);
    *(ushort8*)&Wb[kt * 16384 + col * 64 + ((g ^ (col & 7)) * 8)] = u;
  }
}

// ---------------- fused dual GEMM: hs = bf16((x@W)*dinv) ; res = x@Wr + br ----------------
// BM=128 rows/block, 8 waves (512 thr). Wave w owns rows [brow+w*16, +16), all 256 cols.
// LDS 50 KB -> 3 blocks/CU = 24 waves/CU (75% occupancy); W staged once per 128 rows.
__global__ __launch_bounds__(512) void k_gemm(
    const float* __restrict__ x, const unsigned short* __restrict__ Wb,
    const float* __restrict__ br, const float* __restrict__ dinv,
    unsigned short* __restrict__ hs, float* res, int N)
{
  __shared__ unsigned short xt[128][72];
  __shared__ unsigned short wt[256 * 64];
  int tid = threadIdx.x;
  int lane = tid & 63, w = tid >> 6;
  int lo = lane & 15, hi = lane >> 4;
  int brow = blockIdx.x * 128;

  f32x4 acc[16];
#pragma unroll
  for (int c = 0; c < 16; ++c) acc[c] = (f32x4){0.f, 0.f, 0.f, 0.f};

  for (int kt = 0; kt < 4; ++kt) {
    int k0 = kt * 64;
    // stage W K-tile (32 KB linear image) via async global->LDS, 16B/lane
    const unsigned short* gw = Wb + kt * 16384;
#pragma unroll
    for (int i = 0; i < 4; ++i) {
      int off = i * 4096 + tid * 8;  // ushort offset; lane-linear 16B
      GLOAD_LDS16(gw + off, &wt[off]);
    }
    // stage x tile: 128 rows x 64 k (coalesced float4 loads, bf16 convert)
#pragma unroll
    for (int r = 0; r < 4; ++r) {
      int idx = tid + 512 * r;          // 0..2047
      int row = idx >> 4, kq = idx & 15;
      int node = brow + row;
      float4 v = make_float4(0.f, 0.f, 0.f, 0.f);
      if (node < N) v = *(const float4*)(x + (size_t)node * 256 + k0 + kq * 4);
      ushort4v u;
      u[0] = f2bf(v.x); u[1] = f2bf(v.y); u[2] = f2bf(v.z); u[3] = f2bf(v.w);
      *(ushort4v*)(&xt[row][kq * 4]) = u;
    }
    __syncthreads();
#pragma unroll
    for (int kk = 0; kk < 2; ++kk) {
      bf16x8 a = *(const bf16x8*)(&xt[w * 16 + lo][kk * 32 + hi * 8]);
      int gsw = ((kk * 4 + hi) ^ (lo & 7)) * 8;
#pragma unroll
      for (int c = 0; c < 16; ++c) {
        bf16x8 b = *(const bf16x8*)(&wt[(c * 16 + lo) * 64 + gsw]);
        acc[c] = __builtin_amdgcn_mfma_f32_16x16x32_bf16(a, b, acc[c], 0, 0, 0);
      }
    }
    __syncthreads();
  }
  // epilogue: D row = hi*4+reg, col = lo
#pragma unroll
  for (int c = 0; c < 16; ++c) {
    int colo = c * 16 + lo;
#pragma unroll
    for (int rg = 0; rg < 4; ++rg) {
      int row = brow + w * 16 + hi * 4 + rg;
      if (row < N) {
        float v = acc[c][rg];
        if (colo < 128) hs[(size_t)row * 128 + colo] = f2bf(v * dinv[row]);
        else            res[(size_t)row * 128 + (colo - 128)] = v + br[colo - 128];
      }
    }
  }
}

// ---------------- per-node aggregation + bias + residual + LayerNorm + ReLU ----------------
__global__ __launch_bounds__(256) void k_agg(
    const unsigned int* __restrict__ hsb, const float* resin,
    const float* __restrict__ dinv, const int* __restrict__ start,
    const int* __restrict__ deg, const int* __restrict__ ssrc,
    const float* __restrict__ bias, const float* __restrict__ gamma,
    const float* __restrict__ beta, float* out, int N)
{
  int node = blockIdx.x * 4 + (threadIdx.x >> 6);
  int lane = threadIdx.x & 63;
  if (node >= N) return;
  unsigned int su = hsb[(size_t)node * 64 + lane];  // self-loop (hs already * dinv[src])
  float ax = bflo(su), ay = bfhi(su);
  int s0 = start[node], cnt = deg[node];
  const int* sp = ssrc + s0;
  int e = 0;
  for (; e + 8 <= cnt; e += 8) {
    int i0 = sp[e + 0], i1 = sp[e + 1], i2 = sp[e + 2], i3 = sp[e + 3];
    int i4 = sp[e + 4], i5 = sp[e + 5], i6 = sp[e + 6], i7 = sp[e + 7];
    unsigned int u0 = hsb[(size_t)i0 * 64 + lane];
    unsigned int u1 = hsb[(size_t)i1 * 64 + lane];
    unsigned int u2 = hsb[(size_t)i2 * 64 + lane];
    unsigned int u3 = hsb[(size_t)i3 * 64 + lane];
    unsigned int u4 = hsb[(size_t)i4 * 64 + lane];
    unsigned int u5 = hsb[(size_t)i5 * 64 + lane];
    unsigned int u6 = hsb[(size_t)i6 * 64 + lane];
    unsigned int u7 = hsb[(size_t)i7 * 64 + lane];
    float x01 = bflo(u0) + bflo(u1), x23 = bflo(u2) + bflo(u3);
    float x45 = bflo(u4) + bflo(u5), x67 = bflo(u6) + bflo(u7);
    float y01 = bfhi(u0) + bfhi(u1), y23 = bfhi(u2) + bfhi(u3);
    float y45 = bfhi(u4) + bfhi(u5), y67 = bfhi(u6) + bfhi(u7);
    ax += (x01 + x23) + (x45 + x67);
    ay += (y01 + y23) + (y45 + y67);
  }
  for (; e + 4 <= cnt; e += 4) {
    int i0 = sp[e + 0], i1 = sp[e + 1], i2 = sp[e + 2], i3 = sp[e + 3];
    unsigned int u0 = hsb[(size_t)i0 * 64 + lane];
    unsigned int u1 = hsb[(size_t)i1 * 64 + lane];
    unsigned int u2 = hsb[(size_t)i2 * 64 + lane];
    unsigned int u3 = hsb[(size_t)i3 * 64 + lane];
    ax += (bflo(u0) + bflo(u1)) + (bflo(u2) + bflo(u3));
    ay += (bfhi(u0) + bfhi(u1)) + (bfhi(u2) + bfhi(u3));
  }
  for (; e < cnt; ++e) {
    int s = sp[e];
    unsigned int u = hsb[(size_t)s * 64 + lane];
    ax += bflo(u); ay += bfhi(u);
  }
  float di = dinv[node];
  float2 r  = ((const float2*)resin)[(size_t)node * 64 + lane];
  float2 bb = ((const float2*)bias)[lane];
  float vx = ax * di + bb.x + r.x;
  float vy = ay * di + bb.y + r.y;
  float sum = vx + vy;
#pragma unroll
  for (int off = 32; off >= 1; off >>= 1) sum += __shfl_xor(sum, off, 64);
  float mean = sum * (1.0f / 128.0f);
  float dx = vx - mean, dy = vy - mean;
  float sq = dx * dx + dy * dy;
#pragma unroll
  for (int off = 32; off >= 1; off >>= 1) sq += __shfl_xor(sq, off, 64);
  float rstd = rsqrtf(sq * (1.0f / 128.0f) + 1e-5f);
  float2 g  = ((const float2*)gamma)[lane];
  float2 be = ((const float2*)beta)[lane];
  float ox = fmaxf(dx * rstd * g.x + be.x, 0.0f);
  float oy = fmaxf(dy * rstd * g.y + be.y, 0.0f);
  ((float2*)out)[(size_t)node * 64 + lane] = make_float2(ox, oy);
}

extern "C" void kernel_launch(void* const* d_in, const int* in_sizes, int n_in,
                              void* d_out, int out_size, void* d_ws, size_t ws_size,
                              hipStream_t stream) {
  const float* x     = (const float*)d_in[0];
  const int*   eidx  = (const int*)d_in[1];
  const float* W     = (const float*)d_in[2];
  const float* b     = (const float*)d_in[3];
  const float* Wr    = (const float*)d_in[4];
  const float* br    = (const float*)d_in[5];
  const float* gamma = (const float*)d_in[6];
  const float* beta  = (const float*)d_in[7];
  float* out = (float*)d_out;

  int N = in_sizes[0] / 256;
  int E = in_sizes[1] / 2;
  const int* srcI = eidx;
  const int* dstI = eidx + E;

  char* w = (char*)d_ws;
  size_t off = 0;
  auto alloc = [&](size_t bytes) -> void* {
    void* p = w + off;
    off += (bytes + 255) & ~(size_t)255;
    return p;
  };
  unsigned short* hs   = (unsigned short*)alloc((size_t)N * 128 * 2);
  int*   deg    = (int*)alloc((size_t)N * 4);
  float* dinv   = (float*)alloc((size_t)N * 4);
  int*   start  = (int*)alloc((size_t)N * 4);
  int*   rank   = (int*)alloc((size_t)E * 4);
  int*   ssrc   = (int*)alloc((size_t)E * 4);
  unsigned short* Wb = (unsigned short*)alloc((size_t)4 * 16384 * 2);
  int nb = (N + 1023) / 1024;
  int*   bsums  = (int*)alloc(((size_t)nb + 32) * 4);

  hipMemsetAsync(deg, 0, (size_t)N * 4, stream);
  int egrid = (E / 4 + 255) / 256 + 1;
  k_degrank<<<egrid, 256, 0, stream>>>(dstI, deg, rank, E);
  k_dinv <<<(N + 255) / 256, 256, 0, stream>>>(deg, dinv, N);
  k_scanA<<<nb, 256, 0, stream>>>(deg, bsums, N);
  k_scanB<<<1, 128, 0, stream>>>(bsums, nb);
  k_scanC<<<nb, 256, 0, stream>>>(deg, bsums, start, N);
  k_fill <<<egrid, 256, 0, stream>>>(srcI, dstI, start, rank, ssrc, E);
  k_prepw<<<8, 256, 0, stream>>>(W, Wr, Wb);
  k_gemm <<<(N + 127) / 128, 512, 0, stream>>>(x, Wb, br, dinv, hs, out, N);
  k_agg  <<<(N + 3) / 4, 256, 0, stream>>>((const unsigned int*)hs, out, dinv, start, deg, ssrc,
                                           b, gamma, beta, out, N);
}